// Round 14
// baseline (79.273 us; speedup 1.0000x reference)
//
#include <hip/hip_runtime.h>
#include <math.h>

// Problem constants (B, V, H, NI, E) = (512, 50, 768, 8, 2)
#define B_  512
#define V_  50
#define H_  768
#define NI_ 8
#define M_  (B_ * NI_)   // 4096 MLP rows
#define K1_ (2 * H_)     // 1536
#define NCB_ 12          // gate partial column-blocks (768/64)
#define NROWS_ 25600     // B*V output rows
#define ROWS1_ 15360     // rows copied in mega1 (1536 waves x 10)
#define CPB1_  384       // mega1 copy blocks
#define CPB2_  256       // gate copy blocks (1024 waves x 10 = 10240 rows)

using f32x4 = __attribute__((ext_vector_type(4))) float;
using s16x8 = __attribute__((ext_vector_type(8))) short;

#define SBAR()   asm volatile("s_barrier" ::: "memory")
#define WAITV6() asm volatile("s_waitcnt vmcnt(6)" ::: "memory")
#define WAITV0() asm volatile("s_waitcnt vmcnt(0)" ::: "memory")

__device__ __forceinline__ float gelu_exact(float x) {
    return 0.5f * x * (1.0f + erff(x * 0.7071067811865476f));
}

__device__ __forceinline__ short f2bf(float f) {
    union { float f; unsigned u; } v; v.f = f;
    unsigned r = (v.u + 0x7fffu + ((v.u >> 16) & 1u)) >> 16;  // RNE
    return (short)r;
}

#define GLOAD16(g, l)                                                          \
    __builtin_amdgcn_global_load_lds(                                          \
        (const __attribute__((address_space(1))) void*)(g),                    \
        (__attribute__((address_space(3))) void*)(l), 16, 0, 0)

__device__ __forceinline__ short* lds_ptr(short* base, int row, int byteoff) {
    return (short*)((char*)base + row * 128 + (byteoff ^ ((row & 7) << 4)));
}

// ---------------------------------------------------------------------------
// row-granular winner-skipping copy: each wave copies 10 rows (3KB each as
// 3 x 1KB coalesced segments), skipping rows the blend will write.
// ---------------------------------------------------------------------------
template <int NWAVES>
__device__ __forceinline__ void copy_rows(const float4* __restrict__ cs,
                                          float4* __restrict__ cd,
                                          const int* __restrict__ winner,
                                          int rbase, int gw, int lane) {
    int win[10];
#pragma unroll
    for (int i = 0; i < 10; ++i)
        win[i] = winner[rbase + gw + i * NWAVES];
#pragma unroll
    for (int i = 0; i < 10; ++i) {
        if (win[i] >= 0) continue;
        int row = rbase + gw + i * NWAVES;
        const float4* s = cs + (size_t)row * 192;
        float4* d = cd + (size_t)row * 192;
        float4 t0 = s[lane], t1 = s[lane + 64], t2 = s[lane + 128];
        d[lane] = t0; d[lane + 64] = t1; d[lane + 128] = t2;
    }
}

// ---------------------------------------------------------------------------
// 1) fused preprocessing:
//    blk <  288 : W1 convert+transpose -> W1t [768][1536]
//    blk <  432 : W2 plain convert (row-major) -> W2b [768][768]
//    blk <  576 : Wg1 convert+transpose -> Wg1t [768][768]
//    blk < 1600 : gather X rows (4 rows/block)
//    blk < 1612 : bc[j] = bg1[j] + sum_k b2[k]*Wg1[k][j]
//    blk < 1614 : winner[b*V+v] = last valid i with idx[b,i]==v, else -1
// ---------------------------------------------------------------------------
__global__ __launch_bounds__(256) void pre_kernel(
    const float* __restrict__ vs, const float* __restrict__ iv,
    const int* __restrict__ idx,
    const float* __restrict__ W1, const float* __restrict__ W2,
    const float* __restrict__ Wg1,
    const float* __restrict__ b2, const float* __restrict__ bg1,
    short* __restrict__ W1t, short* __restrict__ W2b, short* __restrict__ Wg1t,
    short* __restrict__ X, float* __restrict__ bc, int* __restrict__ winner) {
    __shared__ short s[64][65];
    const int blk = blockIdx.x;
    const int tid = threadIdx.x;

    if (blk < 288 || (blk >= 432 && blk < 576)) {
        const float* src; short* dst; int K, t;
        if (blk < 288) { src = W1;  dst = W1t;  K = K1_; t = blk; }
        else           { src = Wg1; dst = Wg1t; K = H_;  t = blk - 432; }
        int bx = t % 12, by = t / 12;
        int k0 = by * 64, n0 = bx * 64;
#pragma unroll
        for (int e = 0; e < 16; ++e) {
            int li = tid + e * 256;
            int kk = li >> 6, nn = li & 63;
            s[kk][nn] = f2bf(src[(size_t)(k0 + kk) * H_ + n0 + nn]);
        }
        __syncthreads();
#pragma unroll
        for (int e = 0; e < 16; ++e) {
            int li = tid + e * 256;
            int nn = li >> 6, kk = li & 63;
            dst[(size_t)(n0 + nn) * K + k0 + kk] = s[kk][nn];
        }
    } else if (blk < 432) {
        size_t base = (size_t)(blk - 288) * 4096;
#pragma unroll
        for (int e = 0; e < 4; ++e) {
            size_t i = base + (size_t)e * 1024 + tid * 4;
            float4 a = *(const float4*)(W2 + i);
            short4 o;
            o.x = f2bf(a.x); o.y = f2bf(a.y); o.z = f2bf(a.z); o.w = f2bf(a.w);
            *(short4*)(W2b + i) = o;
        }
    } else if (blk < 1600) {
        int g = blk - 576;                  // 0..1023
        int r = g * 4 + (tid >> 6);         // row 0..4095
        int lane = tid & 63;
        int b = r >> 3;
        int id = idx[r];
        id = min(max(id, 0), V_ - 1);
        const float4* s1 = (const float4*)(vs + ((size_t)b * V_ + id) * H_);
        const float4* s2 = (const float4*)(iv + (size_t)r * H_);
        short* xr = X + (size_t)r * K1_;
#pragma unroll
        for (int part = 0; part < 3; ++part) {
            int e = lane + part * 64;
            float4 a = s1[e];
            float4 c = s2[e];
            short4 oa, oc;
            oa.x = f2bf(a.x); oa.y = f2bf(a.y); oa.z = f2bf(a.z); oa.w = f2bf(a.w);
            oc.x = f2bf(c.x); oc.y = f2bf(c.y); oc.z = f2bf(c.z); oc.w = f2bf(c.w);
            *(short4*)&xr[e * 4] = oa;
            *(short4*)&xr[H_ + e * 4] = oc;
        }
    } else if (blk < 1612) {
        __shared__ float part[4][64];
        int c = blk - 1600;
        int sub = tid >> 6;
        int jj = tid & 63;
        int j = c * 64 + jj;
        float sum = 0.f;
        for (int k = sub * 192; k < sub * 192 + 192; ++k)
            sum += b2[k] * Wg1[(size_t)k * H_ + j];
        part[sub][jj] = sum;
        __syncthreads();
        if (sub == 0)
            bc[j] = part[0][jj] + part[1][jj] + part[2][jj] + part[3][jj] + bg1[j];
    } else {
        int b = (blk - 1612) * 256 + tid;
        if (b < B_) {
            int id[NI_];
#pragma unroll
            for (int i = 0; i < NI_; ++i) id[i] = idx[b * NI_ + i];
            for (int v = 0; v < V_; ++v) {
                int wv = -1;
#pragma unroll
                for (int i = 0; i < NI_; ++i)
                    if (id[i] == v) wv = i;  // v in [0,V) => valid
                winner[b * V_ + v] = wv;
            }
        }
    }
}

// ---------------------------------------------------------------------------
// shared GEMM core (R11, proven 74.8): BM=128, BN=64, BK=64, 4 waves.
// Dbuf global_load_lds w16 prefetch, counted vmcnt(6) (T4), raw s_barrier;
// pre-swizzled global source <-> XOR-swizzled ds_read (rule #21). No setprio.
// GATE=1: no C write; emit per-64-col gate partials.
// ---------------------------------------------------------------------------
template <int ACT, int GATE>
__device__ __forceinline__ void gemm_core(
    const short* __restrict__ A, const short* __restrict__ Bt,
    const float* __restrict__ bias, short* __restrict__ C,
    int N, int K, int row0, int col0, int bx,
    const float* __restrict__ wg2, float* __restrict__ gate_part,
    short (*As)[128 * 64], short (*Bs)[64 * 64], int tid) {
    const int lane = tid & 63;
    const int wave = tid >> 6;
    const int llo = lane & 15;
    const int lhi = lane >> 4;

    const short* gsrc[6];
    short* ldst0[6];
    int lstep[6];
#pragma unroll
    for (int p = 0; p < 6; ++p) {
        int c = wave * 6 + p;
        int jj = lane & 7;
        if (c < 16) {
            int r = c * 8 + (lane >> 3);
            int j = jj ^ (r & 7);
            gsrc[p] = A + (size_t)(row0 + r) * K + j * 8;
            ldst0[p] = &As[0][c * 512];
            lstep[p] = 128 * 64;
        } else {
            int r = (c - 16) * 8 + (lane >> 3);
            int j = jj ^ (r & 7);
            gsrc[p] = Bt + (size_t)(col0 + r) * K + j * 8;
            ldst0[p] = &Bs[0][(c - 16) * 512];
            lstep[p] = 64 * 64;
        }
    }

    f32x4 acc[2][4];
#pragma unroll
    for (int mi = 0; mi < 2; ++mi)
#pragma unroll
        for (int nf = 0; nf < 4; ++nf) acc[mi][nf] = (f32x4){0, 0, 0, 0};

    const int nt = K >> 6;
#pragma unroll
    for (int p = 0; p < 6; ++p) GLOAD16(gsrc[p], ldst0[p]);

    for (int t = 0; t < nt; ++t) {
        const int cur = t & 1;
        if (t + 1 < nt) {
#pragma unroll
            for (int p = 0; p < 6; ++p)
                GLOAD16(gsrc[p] + (size_t)(t + 1) * 64,
                        ldst0[p] + (cur ^ 1) * lstep[p]);
            WAITV6();   // tile t resident; tile t+1's loads stay in flight
        } else {
            WAITV0();
        }
        SBAR();

        short* Ab = (short*)As[cur];
        short* Bb = (short*)Bs[cur];
#pragma unroll
        for (int ks = 0; ks < 2; ++ks) {
            s16x8 a[2], b[4];
#pragma unroll
            for (int mi = 0; mi < 2; ++mi)
                a[mi] = *(const s16x8*)lds_ptr(Ab, wave * 32 + mi * 16 + llo,
                                               ks * 64 + lhi * 16);
#pragma unroll
            for (int nf = 0; nf < 4; ++nf)
                b[nf] = *(const s16x8*)lds_ptr(Bb, nf * 16 + llo,
                                               ks * 64 + lhi * 16);
#pragma unroll
            for (int mi = 0; mi < 2; ++mi)
#pragma unroll
                for (int nf = 0; nf < 4; ++nf)
                    acc[mi][nf] = __builtin_amdgcn_mfma_f32_16x16x32_bf16(
                        a[mi], b[nf], acc[mi][nf], 0, 0, 0);
        }
        SBAR();
    }

    if (!GATE) {
        // C/D layout: col=lane&15, row=(lane>>4)*4+j
#pragma unroll
        for (int nf = 0; nf < 4; ++nf) {
            int cc = col0 + nf * 16 + llo;
            float bv = bias ? bias[cc] : 0.0f;
#pragma unroll
            for (int mi = 0; mi < 2; ++mi) {
#pragma unroll
                for (int j = 0; j < 4; ++j) {
                    int rr = row0 + wave * 32 + mi * 16 + lhi * 4 + j;
                    float v = acc[mi][nf][j] + bv;
                    if (ACT) v = gelu_exact(v);
                    C[(size_t)rr * N + cc] = f2bf(v);
                }
            }
        }
    } else {
        float s[2][4];
#pragma unroll
        for (int mi = 0; mi < 2; ++mi)
#pragma unroll
            for (int j = 0; j < 4; ++j) s[mi][j] = 0.f;
#pragma unroll
        for (int nf = 0; nf < 4; ++nf) {
            int cc = col0 + nf * 16 + llo;
            float bv = bias[cc];
            float wv = wg2[cc];
#pragma unroll
            for (int mi = 0; mi < 2; ++mi)
#pragma unroll
                for (int j = 0; j < 4; ++j)
                    s[mi][j] += gelu_exact(acc[mi][nf][j] + bv) * wv;
        }
#pragma unroll
        for (int off = 1; off < 16; off <<= 1)
#pragma unroll
            for (int mi = 0; mi < 2; ++mi)
#pragma unroll
                for (int j = 0; j < 4; ++j)
                    s[mi][j] += __shfl_xor(s[mi][j], off);
        if (llo == 0) {
#pragma unroll
            for (int mi = 0; mi < 2; ++mi)
#pragma unroll
                for (int j = 0; j < 4; ++j) {
                    int rr = row0 + wave * 32 + mi * 16 + lhi * 4 + j;
                    gate_part[(size_t)rr * NCB_ + bx] = s[mi][j];
                }
        }
    }
}

// ---------------------------------------------------------------------------
// 2) mega1 (840 blocks):
//    [0,384)   GEMM1 h1=gelu(X@W1t^T+b1), grid 12x32, XCD swizzle
//    [384,456) Wct[n][k] = sum_j Wg1t[n][j]*W2b[k][j]  (=(W2@Wg1)^T)
//    [456,840) copy rows [0, ROWS1) skipping winner rows
// ---------------------------------------------------------------------------
__global__ __launch_bounds__(256) void mega1(
    const short* __restrict__ Xb, const short* __restrict__ W1t,
    const float* __restrict__ b1, short* __restrict__ h1b,
    const short* __restrict__ Wg1t, const short* __restrict__ W2b,
    short* __restrict__ Wct, const int* __restrict__ winner,
    const float4* __restrict__ cs, float4* __restrict__ cd) {
    __shared__ short As[2][128 * 64];  // 32 KB
    __shared__ short Bs[2][64 * 64];   // 16 KB
    const int bid = blockIdx.x;
    const int tid = threadIdx.x;

    if (bid < 384) {
        int sw = (bid & 7) * 48 + (bid >> 3);  // XCD swizzle (384%8==0)
        int bx = sw % 12, by = sw / 12;
        gemm_core<1, 0>(Xb, W1t, b1, h1b, H_, K1_, by * 128, bx * 64, bx,
                        nullptr, nullptr, As, Bs, tid);
    } else if (bid < 456) {
        int t = bid - 384;                     // 72 blocks: 6 x 12
        int bx = t % 12, by = t / 12;
        gemm_core<0, 0>(Wg1t, W2b, nullptr, Wct, H_, H_, by * 128, bx * 64, bx,
                        nullptr, nullptr, As, Bs, tid);
    } else {
        int gw = (bid - 456) * 4 + (tid >> 6);  // 0..1535
        copy_rows<CPB1_ * 4>(cs, cd, winner, 0, gw, tid & 63);
    }
}

// ---------------------------------------------------------------------------
// 3) gate kernel (640 blocks):
//    [0,384)   gate partials from gelu(h1@Wct^T+bc)·Wg2, grid 12x32
//    [384,640) copy rows [ROWS1, NROWS) skipping winner rows
// ---------------------------------------------------------------------------
__global__ __launch_bounds__(256) void gate_gemm(
    const short* __restrict__ h1b, const short* __restrict__ Wct,
    const float* __restrict__ bc, const float* __restrict__ wg2,
    float* __restrict__ gate_part, const int* __restrict__ winner,
    const float4* __restrict__ cs, float4* __restrict__ cd) {
    __shared__ short As[2][128 * 64];
    __shared__ short Bs[2][64 * 64];
    const int bid = blockIdx.x;
    const int tid = threadIdx.x;

    if (bid < 384) {
        int sw = (bid & 7) * 48 + (bid >> 3);
        int bx = sw % 12, by = sw / 12;
        gemm_core<1, 1>(h1b, Wct, bc, nullptr, H_, H_, by * 128, bx * 64, bx,
                        wg2, gate_part, As, Bs, tid);
    } else {
        int gw = (bid - 384) * 4 + (tid >> 6);  // 0..1023
        copy_rows<CPB2_ * 4>(cs, cd, winner, ROWS1_, gw, tid & 63);
    }
}

// ---------------------------------------------------------------------------
// 4) final blend: winner rows only (table-driven; copy skipped these rows)
// ---------------------------------------------------------------------------
__global__ __launch_bounds__(192) void final_blend(
    const float* __restrict__ vs, const float* __restrict__ iv,
    const int* __restrict__ idx, const int* __restrict__ winner,
    const float* __restrict__ gate_part, const float* __restrict__ bg2,
    float* __restrict__ out) {
    int r = blockIdx.x;  // b*NI + i
    int b = r >> 3, i = r & 7;
    int id = idx[r];
    if (id < 0 || id >= V_) return;
    if (winner[b * V_ + id] != i) return;  // only the winning write executes
    __shared__ float gsh;
    if (threadIdx.x == 0) {
        float s = bg2[0];
#pragma unroll
        for (int c = 0; c < NCB_; ++c) s += gate_part[(size_t)r * NCB_ + c];
        gsh = 1.f / (1.f + expf(-s));
    }
    __syncthreads();
    float g = gsh;
    int t = threadIdx.x;
    const float4* src = (const float4*)(vs + ((size_t)b * V_ + id) * H_);
    const float4* ivr = (const float4*)(iv + (size_t)r * H_);
    float4* dst = (float4*)(out + ((size_t)b * V_ + id) * H_);
    float4 o = src[t], x = ivr[t], res;
    res.x = o.x * (1.f - g) + x.x * g;
    res.y = o.y * (1.f - g) + x.y * g;
    res.z = o.z * (1.f - g) + x.z * g;
    res.w = o.w * (1.f - g) + x.w * g;
    dst[t] = res;
}

// ---------------------------------------------------------------------------
extern "C" void kernel_launch(void* const* d_in, const int* in_sizes, int n_in,
                              void* d_out, int out_size, void* d_ws, size_t ws_size,
                              hipStream_t stream) {
    const float* vs  = (const float*)d_in[0];
    const float* iv  = (const float*)d_in[2];
    const float* W1  = (const float*)d_in[3];
    const float* b1  = (const float*)d_in[4];
    const float* W2  = (const float*)d_in[5];
    const float* b2  = (const float*)d_in[6];
    const float* Wg1 = (const float*)d_in[7];
    const float* bg1 = (const float*)d_in[8];
    const float* Wg2 = (const float*)d_in[9];
    const float* bg2 = (const float*)d_in[10];
    const int*   idx = (const int*)d_in[11];
    float* out = (float*)d_out;

    // workspace layout (~25.2 MB)
    char* ws = (char*)d_ws;
    short* Xb   = (short*)ws;                                   // 12.58 MB
    short* h1b  = (short*)(ws + (size_t)M_ * K1_ * 2);          // 6.29 MB
    float* gate_part = (float*)(ws + (size_t)M_ * K1_ * 2 + (size_t)M_ * H_ * 2);
    int*   winner = (int*)((char*)gate_part + (size_t)M_ * NCB_ * 4);  // 100 KB
    short* W1t  = (short*)((char*)winner + (size_t)NROWS_ * 4);
    short* W2b  = W1t + (size_t)H_ * K1_;
    short* Wg1t = W2b + (size_t)H_ * H_;
    short* Wct  = Wg1t + (size_t)H_ * H_;
    float* bc   = (float*)(Wct + (size_t)H_ * H_);

    const float4* cs = (const float4*)vs;
    float4* cd = (float4*)out;

    // 1) preprocessing (converts + gather + bias fold + winner table)
    pre_kernel<<<1614, 256, 0, stream>>>(vs, iv, idx, W1, W2, Wg1, b2, bg1,
                                         W1t, W2b, Wg1t, Xb, bc, winner);
    // 2) GEMM1 (384) + Wct (72) + 60% row-copy (384)
    mega1<<<840, 256, 0, stream>>>(Xb, W1t, b1, h1b, Wg1t, W2b, Wct, winner,
                                   cs, cd);
    // 3) gate partials (384) + 40% row-copy (256)
    gate_gemm<<<640, 256, 0, stream>>>(h1b, Wct, bc, Wg2, gate_part, winner,
                                       cs, cd);
    // 4) blend winner rows (the only writes to those rows)
    final_blend<<<M_, 192, 0, stream>>>(vs, iv, idx, winner, gate_part, bg2, out);
}

// Round 15
// 74.576 us; speedup vs baseline: 1.0630x; 1.0630x over previous
//
#include <hip/hip_runtime.h>
#include <math.h>

// Problem constants (B, V, H, NI, E) = (512, 50, 768, 8, 2)
#define B_  512
#define V_  50
#define H_  768
#define NI_ 8
#define M_  (B_ * NI_)   // 4096 MLP rows
#define K1_ (2 * H_)     // 1536
#define NCB_ 12          // gate partial column-blocks (768/64)
#define N4_     4915200  // B*V*H/4 float4 of the output
#define SPLIT4_ 2949120  // copied during mega1 = 384*256*30; rest during gate
#define CPB1_   384      // mega1 copy blocks (30 float4/thread)
#define CPB2_   256      // gate copy blocks  (30 float4/thread)

using f32x4 = __attribute__((ext_vector_type(4))) float;
using s16x8 = __attribute__((ext_vector_type(8))) short;

#define SBAR()   asm volatile("s_barrier" ::: "memory")
#define WAITV6() asm volatile("s_waitcnt vmcnt(6)" ::: "memory")
#define WAITV0() asm volatile("s_waitcnt vmcnt(0)" ::: "memory")

__device__ __forceinline__ float gelu_exact(float x) {
    return 0.5f * x * (1.0f + erff(x * 0.7071067811865476f));
}

__device__ __forceinline__ short f2bf(float f) {
    union { float f; unsigned u; } v; v.f = f;
    unsigned r = (v.u + 0x7fffu + ((v.u >> 16) & 1u)) >> 16;  // RNE
    return (short)r;
}

#define GLOAD16(g, l)                                                          \
    __builtin_amdgcn_global_load_lds(                                          \
        (const __attribute__((address_space(1))) void*)(g),                    \
        (__attribute__((address_space(3))) void*)(l), 16, 0, 0)

__device__ __forceinline__ short* lds_ptr(short* base, int row, int byteoff) {
    return (short*)((char*)base + row * 128 + (byteoff ^ ((row & 7) << 4)));
}

// ---------------------------------------------------------------------------
// 1) fused preprocessing:
//    blk <  288 : W1 convert+transpose -> W1t [768][1536]
//    blk <  432 : W2 plain convert (row-major) -> W2b [768][768]
//    blk <  576 : Wg1 convert+transpose -> Wg1t [768][768]
//    blk < 1600 : gather X rows (4 rows/block)
//    else (12)  : bc[j] = bg1[j] + sum_k b2[k]*Wg1[k][j]
// ---------------------------------------------------------------------------
__global__ __launch_bounds__(256) void pre_kernel(
    const float* __restrict__ vs, const float* __restrict__ iv,
    const int* __restrict__ idx,
    const float* __restrict__ W1, const float* __restrict__ W2,
    const float* __restrict__ Wg1,
    const float* __restrict__ b2, const float* __restrict__ bg1,
    short* __restrict__ W1t, short* __restrict__ W2b, short* __restrict__ Wg1t,
    short* __restrict__ X, float* __restrict__ bc) {
    __shared__ short s[64][65];
    const int blk = blockIdx.x;
    const int tid = threadIdx.x;

    if (blk < 288 || (blk >= 432 && blk < 576)) {
        const float* src; short* dst; int K, t;
        if (blk < 288) { src = W1;  dst = W1t;  K = K1_; t = blk; }
        else           { src = Wg1; dst = Wg1t; K = H_;  t = blk - 432; }
        int bx = t % 12, by = t / 12;
        int k0 = by * 64, n0 = bx * 64;
#pragma unroll
        for (int e = 0; e < 16; ++e) {
            int li = tid + e * 256;
            int kk = li >> 6, nn = li & 63;
            s[kk][nn] = f2bf(src[(size_t)(k0 + kk) * H_ + n0 + nn]);
        }
        __syncthreads();
#pragma unroll
        for (int e = 0; e < 16; ++e) {
            int li = tid + e * 256;
            int nn = li >> 6, kk = li & 63;
            dst[(size_t)(n0 + nn) * K + k0 + kk] = s[kk][nn];
        }
    } else if (blk < 432) {
        size_t base = (size_t)(blk - 288) * 4096;
#pragma unroll
        for (int e = 0; e < 4; ++e) {
            size_t i = base + (size_t)e * 1024 + tid * 4;
            float4 a = *(const float4*)(W2 + i);
            short4 o;
            o.x = f2bf(a.x); o.y = f2bf(a.y); o.z = f2bf(a.z); o.w = f2bf(a.w);
            *(short4*)(W2b + i) = o;
        }
    } else if (blk < 1600) {
        int g = blk - 576;                  // 0..1023
        int r = g * 4 + (tid >> 6);         // row 0..4095
        int lane = tid & 63;
        int b = r >> 3;
        int id = idx[r];
        id = min(max(id, 0), V_ - 1);
        const float4* s1 = (const float4*)(vs + ((size_t)b * V_ + id) * H_);
        const float4* s2 = (const float4*)(iv + (size_t)r * H_);
        short* xr = X + (size_t)r * K1_;
#pragma unroll
        for (int part = 0; part < 3; ++part) {
            int e = lane + part * 64;
            float4 a = s1[e];
            float4 c = s2[e];
            short4 oa, oc;
            oa.x = f2bf(a.x); oa.y = f2bf(a.y); oa.z = f2bf(a.z); oa.w = f2bf(a.w);
            oc.x = f2bf(c.x); oc.y = f2bf(c.y); oc.z = f2bf(c.z); oc.w = f2bf(c.w);
            *(short4*)&xr[e * 4] = oa;
            *(short4*)&xr[H_ + e * 4] = oc;
        }
    } else {
        __shared__ float part[4][64];
        int c = blk - 1600;
        int sub = tid >> 6;
        int jj = tid & 63;
        int j = c * 64 + jj;
        float sum = 0.f;
        for (int k = sub * 192; k < sub * 192 + 192; ++k)
            sum += b2[k] * Wg1[(size_t)k * H_ + j];
        part[sub][jj] = sum;
        __syncthreads();
        if (sub == 0)
            bc[j] = part[0][jj] + part[1][jj] + part[2][jj] + part[3][jj] + bg1[j];
    }
}

// ---------------------------------------------------------------------------
// copy: exactly 30 float4/thread as six 5-deep batches
// ---------------------------------------------------------------------------
template <int NBLK>
__device__ __forceinline__ void copy6x5(const float4* __restrict__ cs,
                                        float4* __restrict__ cd,
                                        size_t start, int lb, int tid) {
    const size_t step = (size_t)NBLK * 256;
    size_t base = start + (size_t)lb * 256 + tid;
#pragma unroll
    for (int o = 0; o < 6; ++o) {
        float4 t[5];
#pragma unroll
        for (int u = 0; u < 5; ++u)
            t[u] = cs[base + (size_t)(o * 5 + u) * step];
#pragma unroll
        for (int u = 0; u < 5; ++u)
            cd[base + (size_t)(o * 5 + u) * step] = t[u];
    }
}

// ---------------------------------------------------------------------------
// shared GEMM core: BM=128, BN=64, BK=64, 4 waves (each 32 rows x 64 cols).
// Double-buffered global_load_lds w16 prefetch with COUNTED vmcnt(6) so next
// tile's loads stay in flight across the barrier (T4); raw s_barrier (no
// compiler vmcnt(0) drain). Pre-swizzled src <-> XOR ds_read (rule #21).
// GATE=1: no C write; emit gate partials per 64-col block.
// ---------------------------------------------------------------------------
template <int ACT, int GATE>
__device__ __forceinline__ void gemm_core(
    const short* __restrict__ A, const short* __restrict__ Bt,
    const float* __restrict__ bias, short* __restrict__ C,
    int N, int K, int row0, int col0, int bx,
    const float* __restrict__ wg2, float* __restrict__ gate_part,
    short (*As)[128 * 64], short (*Bs)[64 * 64], int tid) {
    const int lane = tid & 63;
    const int wave = tid >> 6;
    const int llo = lane & 15;
    const int lhi = lane >> 4;

    const short* gsrc[6];
    short* ldst0[6];
    int lstep[6];
#pragma unroll
    for (int p = 0; p < 6; ++p) {
        int c = wave * 6 + p;
        int jj = lane & 7;
        if (c < 16) {
            int r = c * 8 + (lane >> 3);
            int j = jj ^ (r & 7);
            gsrc[p] = A + (size_t)(row0 + r) * K + j * 8;
            ldst0[p] = &As[0][c * 512];
            lstep[p] = 128 * 64;
        } else {
            int r = (c - 16) * 8 + (lane >> 3);
            int j = jj ^ (r & 7);
            gsrc[p] = Bt + (size_t)(col0 + r) * K + j * 8;
            ldst0[p] = &Bs[0][(c - 16) * 512];
            lstep[p] = 64 * 64;
        }
    }

    f32x4 acc[2][4];
#pragma unroll
    for (int mi = 0; mi < 2; ++mi)
#pragma unroll
        for (int nf = 0; nf < 4; ++nf) acc[mi][nf] = (f32x4){0, 0, 0, 0};

    const int nt = K >> 6;
#pragma unroll
    for (int p = 0; p < 6; ++p) GLOAD16(gsrc[p], ldst0[p]);

    for (int t = 0; t < nt; ++t) {
        const int cur = t & 1;
        if (t + 1 < nt) {
#pragma unroll
            for (int p = 0; p < 6; ++p)
                GLOAD16(gsrc[p] + (size_t)(t + 1) * 64,
                        ldst0[p] + (cur ^ 1) * lstep[p]);
            WAITV6();   // tile t's 6 loads done; tile t+1's 6 stay in flight
        } else {
            WAITV0();   // last tile: drain
        }
        SBAR();         // all waves' tile-t data resident in LDS

        short* Ab = (short*)As[cur];
        short* Bb = (short*)Bs[cur];
#pragma unroll
        for (int ks = 0; ks < 2; ++ks) {
            s16x8 a[2], b[4];
#pragma unroll
            for (int mi = 0; mi < 2; ++mi)
                a[mi] = *(const s16x8*)lds_ptr(Ab, wave * 32 + mi * 16 + llo,
                                               ks * 64 + lhi * 16);
#pragma unroll
            for (int nf = 0; nf < 4; ++nf)
                b[nf] = *(const s16x8*)lds_ptr(Bb, nf * 16 + llo,
                                               ks * 64 + lhi * 16);
#pragma unroll
            for (int mi = 0; mi < 2; ++mi)
#pragma unroll
                for (int nf = 0; nf < 4; ++nf)
                    acc[mi][nf] = __builtin_amdgcn_mfma_f32_16x16x32_bf16(
                        a[mi], b[nf], acc[mi][nf], 0, 0, 0);
        }
        // compiler drains lgkmcnt before MFMA use; reads done before here.
        SBAR();         // all waves done reading buf[cur]; safe to overwrite
    }

    if (!GATE) {
        // C/D layout: col=lane&15, row=(lane>>4)*4+j
#pragma unroll
        for (int nf = 0; nf < 4; ++nf) {
            int cc = col0 + nf * 16 + llo;
            float bv = bias ? bias[cc] : 0.0f;
#pragma unroll
            for (int mi = 0; mi < 2; ++mi) {
#pragma unroll
                for (int j = 0; j < 4; ++j) {
                    int rr = row0 + wave * 32 + mi * 16 + lhi * 4 + j;
                    float v = acc[mi][nf][j] + bv;
                    if (ACT) v = gelu_exact(v);
                    C[(size_t)rr * N + cc] = f2bf(v);
                }
            }
        }
    } else {
        float s[2][4];
#pragma unroll
        for (int mi = 0; mi < 2; ++mi)
#pragma unroll
            for (int j = 0; j < 4; ++j) s[mi][j] = 0.f;
#pragma unroll
        for (int nf = 0; nf < 4; ++nf) {
            int cc = col0 + nf * 16 + llo;
            float bv = bias[cc];
            float wv = wg2[cc];
#pragma unroll
            for (int mi = 0; mi < 2; ++mi)
#pragma unroll
                for (int j = 0; j < 4; ++j)
                    s[mi][j] += gelu_exact(acc[mi][nf][j] + bv) * wv;
        }
#pragma unroll
        for (int off = 1; off < 16; off <<= 1)
#pragma unroll
            for (int mi = 0; mi < 2; ++mi)
#pragma unroll
                for (int j = 0; j < 4; ++j)
                    s[mi][j] += __shfl_xor(s[mi][j], off);
        if (llo == 0) {
#pragma unroll
            for (int mi = 0; mi < 2; ++mi)
#pragma unroll
                for (int j = 0; j < 4; ++j) {
                    int rr = row0 + wave * 32 + mi * 16 + lhi * 4 + j;
                    gate_part[(size_t)rr * NCB_ + bx] = s[mi][j];
                }
        }
    }
}

// ---------------------------------------------------------------------------
// 2) mega1 (840 blocks):
//    [0,384)   GEMM1 h1=gelu(X@W1t^T+b1), grid 12x32, XCD swizzle
//    [384,456) Wct[n][k] = sum_j Wg1t[n][j]*W2b[k][j]  (=(W2@Wg1)^T)
//    [456,840) copy out[0, SPLIT4)  (384 blocks, 30 float4/thread)
// ---------------------------------------------------------------------------
__global__ __launch_bounds__(256) void mega1(
    const short* __restrict__ Xb, const short* __restrict__ W1t,
    const float* __restrict__ b1, short* __restrict__ h1b,
    const short* __restrict__ Wg1t, const short* __restrict__ W2b,
    short* __restrict__ Wct,
    const float4* __restrict__ cs, float4* __restrict__ cd) {
    __shared__ short As[2][128 * 64];  // 32 KB
    __shared__ short Bs[2][64 * 64];   // 16 KB
    const int bid = blockIdx.x;
    const int tid = threadIdx.x;

    if (bid < 384) {
        int sw = (bid & 7) * 48 + (bid >> 3);  // XCD swizzle (384%8==0)
        int bx = sw % 12, by = sw / 12;
        gemm_core<1, 0>(Xb, W1t, b1, h1b, H_, K1_, by * 128, bx * 64, bx,
                        nullptr, nullptr, As, Bs, tid);
    } else if (bid < 456) {
        int t = bid - 384;                     // 72 blocks: 6 x 12
        int bx = t % 12, by = t / 12;
        gemm_core<0, 0>(Wg1t, W2b, nullptr, Wct, H_, H_, by * 128, bx * 64, bx,
                        nullptr, nullptr, As, Bs, tid);
    } else {
        copy6x5<CPB1_>(cs, cd, 0, bid - 456, tid);
    }
}

// ---------------------------------------------------------------------------
// 3) gate kernel (640 blocks):
//    [0,384)   gate partials from gelu(h1@Wct^T+bc)·Wg2, grid 12x32
//    [384,640) copy out[SPLIT4, N4)  (256 blocks, 30 float4/thread)
// ---------------------------------------------------------------------------
__global__ __launch_bounds__(256) void gate_gemm(
    const short* __restrict__ h1b, const short* __restrict__ Wct,
    const float* __restrict__ bc, const float* __restrict__ wg2,
    float* __restrict__ gate_part,
    const float4* __restrict__ cs, float4* __restrict__ cd) {
    __shared__ short As[2][128 * 64];
    __shared__ short Bs[2][64 * 64];
    const int bid = blockIdx.x;
    const int tid = threadIdx.x;

    if (bid < 384) {
        int sw = (bid & 7) * 48 + (bid >> 3);
        int bx = sw % 12, by = sw / 12;
        gemm_core<1, 1>(h1b, Wct, bc, nullptr, H_, H_, by * 128, bx * 64, bx,
                        wg2, gate_part, As, Bs, tid);
    } else {
        copy6x5<CPB2_>(cs, cd, SPLIT4_, bid - 384, tid);
    }
}

// ---------------------------------------------------------------------------
// 4) final blend: winner rows only (last-write-wins recomputed inline)
// ---------------------------------------------------------------------------
__global__ __launch_bounds__(192) void final_blend(
    const float* __restrict__ vs, const float* __restrict__ iv,
    const int* __restrict__ idx, const float* __restrict__ gate_part,
    const float* __restrict__ bg2, float* __restrict__ out) {
    int r = blockIdx.x;  // b*NI + i
    int b = r >> 3, i = r & 7;
    int id = idx[r];
    if (id < 0 || id >= V_) return;
    for (int j = i + 1; j < NI_; ++j)
        if (idx[b * NI_ + j] == id) return;  // a later valid write wins
    __shared__ float gsh;
    if (threadIdx.x == 0) {
        float s = bg2[0];
#pragma unroll
        for (int c = 0; c < NCB_; ++c) s += gate_part[(size_t)r * NCB_ + c];
        gsh = 1.f / (1.f + expf(-s));
    }
    __syncthreads();
    float g = gsh;
    int t = threadIdx.x;
    const float4* src = (const float4*)(vs + ((size_t)b * V_ + id) * H_);
    const float4* ivr = (const float4*)(iv + (size_t)r * H_);
    float4* dst = (float4*)(out + ((size_t)b * V_ + id) * H_);
    float4 o = src[t], x = ivr[t], res;
    res.x = o.x * (1.f - g) + x.x * g;
    res.y = o.y * (1.f - g) + x.y * g;
    res.z = o.z * (1.f - g) + x.z * g;
    res.w = o.w * (1.f - g) + x.w * g;
    dst[t] = res;
}

// ---------------------------------------------------------------------------
extern "C" void kernel_launch(void* const* d_in, const int* in_sizes, int n_in,
                              void* d_out, int out_size, void* d_ws, size_t ws_size,
                              hipStream_t stream) {
    const float* vs  = (const float*)d_in[0];
    const float* iv  = (const float*)d_in[2];
    const float* W1  = (const float*)d_in[3];
    const float* b1  = (const float*)d_in[4];
    const float* W2  = (const float*)d_in[5];
    const float* b2  = (const float*)d_in[6];
    const float* Wg1 = (const float*)d_in[7];
    const float* bg1 = (const float*)d_in[8];
    const float* Wg2 = (const float*)d_in[9];
    const float* bg2 = (const float*)d_in[10];
    const int*   idx = (const int*)d_in[11];
    float* out = (float*)d_out;

    // workspace layout (~25.3 MB)
    char* ws = (char*)d_ws;
    short* Xb   = (short*)ws;                                   // 12.58 MB
    short* h1b  = (short*)(ws + (size_t)M_ * K1_ * 2);          // 6.29 MB
    float* gate_part = (float*)(ws + (size_t)M_ * K1_ * 2 + (size_t)M_ * H_ * 2);
    short* W1t  = (short*)((char*)gate_part + (size_t)M_ * NCB_ * 4);
    short* W2b  = W1t + (size_t)H_ * K1_;
    short* Wg1t = W2b + (size_t)H_ * H_;
    short* Wct  = Wg1t + (size_t)H_ * H_;
    float* bc   = (float*)(Wct + (size_t)H_ * H_);

    const float4* cs = (const float4*)vs;
    float4* cd = (float4*)out;

    // 1) fused preprocessing (weight converts + gather + bias fold)
    pre_kernel<<<1612, 256, 0, stream>>>(vs, iv, idx, W1, W2, Wg1, b2, bg1,
                                         W1t, W2b, Wg1t, Xb, bc);
    // 2) GEMM1 (384) + Wct (72) + 60% copy (384)
    mega1<<<840, 256, 0, stream>>>(Xb, W1t, b1, h1b, Wg1t, W2b, Wct, cs, cd);
    // 3) gate partials (384) + 40% copy (256)
    gate_gemm<<<640, 256, 0, stream>>>(h1b, Wct, bc, Wg2, gate_part, cs, cd);
    // 4) blend winner rows
    final_blend<<<M_, 192, 0, stream>>>(vs, iv, idx, gate_part, bg2, out);
}